// Round 4
// baseline (426.822 us; speedup 1.0000x reference)
//
#include <hip/hip_runtime.h>
#include <hip/hip_cooperative_groups.h>

namespace cg = cooperative_groups;

#define NB  256
#define NT  512
// dynamic LDS layout (floats): x_lds[64*64]=4096 | red[8][4][512]=16384 | vg[4][512]=2048
#define LDSF (4096 + 16384 + 2048)

__device__ __forceinline__ float4 f4add(float4 a, float4 b) {
    return make_float4(a.x + b.x, a.y + b.y, a.z + b.z, a.w + b.w);
}
__device__ __forceinline__ float4 f4shfl_xor(float4 v, int m) {
    return make_float4(__shfl_xor(v.x, m, 64), __shfl_xor(v.y, m, 64),
                       __shfl_xor(v.z, m, 64), __shfl_xor(v.w, m, 64));
}
__device__ __forceinline__ float squash_scale(float n2) {
    return n2 / (1.f + n2) * rsqrtf(n2 + 1e-7f);
}

// One cooperative kernel: W register-resident for all 3 routing passes.
// Thread map: wave w = i-slot (8 i's/block), lane l: o = l&31, kk = l>>5 (k-half).
// Per-thread W = W[i][o][:][kk*8..+8] = 64 floats.
// n2p[p][b][q][o] = sum over the quarter's 4 k's of s^2 — per-(b,o) squash norms
// are assembled by summing the 4 quarters (squash axis=-1 is over k for each o!).
__global__ __launch_bounds__(NT)
__attribute__((amdgpu_waves_per_eu(2, 2)))
void caps_coop(const float* __restrict__ x,   // [64][2048][8]
               const float* __restrict__ W,   // [2048][32][8][16]
               float* __restrict__ part,      // [256][64][512]  e = k*32+o
               float* __restrict__ s2,        // [3][64][512]
               float* __restrict__ n2p,       // [3][64][4][32]
               float* __restrict__ out)       // [64][32][16]
{
    extern __shared__ float lds[];
    float* x_lds = lds;            // [b][il*8+d]
    float* red   = lds + 4096;     // [slot=w][bq][e]
    float* vg    = lds + 20480;    // [bq][e]

    cg::grid_group grid = cg::this_grid();

    const int t  = threadIdx.x;
    const int w  = t >> 6;
    const int l  = t & 63;
    const int o  = l & 31;
    const int kk = l >> 5;
    const int ch = blockIdx.x;
    const int i  = ch * 8 + w;

    // ---- W[i][o][d][kk-half] -> 64 registers (ONCE for all passes) ---------
    float Wr[8][8];
    {
        const float* wp = W + (size_t)(i * 32 + o) * 128 + kk * 8;
        #pragma unroll
        for (int d = 0; d < 8; ++d) {
            float4 a = *(const float4*)(wp + d * 16);
            float4 b = *(const float4*)(wp + d * 16 + 4);
            Wr[d][0] = a.x; Wr[d][1] = a.y; Wr[d][2] = a.z; Wr[d][3] = a.w;
            Wr[d][4] = b.x; Wr[d][5] = b.y; Wr[d][6] = b.z; Wr[d][7] = b.w;
        }
    }
    // ---- x[:, chunk, :] -> LDS (ONCE) --------------------------------------
    {
        const int f = t * 8;
        const int b = f >> 6;
        const int r = f & 63;
        const float* xp = x + (size_t)b * 16384 + (size_t)ch * 64 + r;
        *(float4*)&x_lds[f]     = *(const float4*)xp;
        *(float4*)&x_lds[f + 4] = *(const float4*)(xp + 4);
    }

    for (int p = 0; p < 3; ++p) {
        for (int g = 0; g < 16; ++g) {          // 4 b's per group
            if (p > 0) {
                // stage vsum for this group's 4 b's, per-(b,o) squash scales
                const int bq  = t >> 7;
                const int b   = g * 4 + bq;
                const int idx = t & 127;
                const int e4  = idx * 4;
                const int ob  = (idx & 7) * 4;   // o of the 4 consecutive e's
                float4 acc = make_float4(0.f, 0.f, 0.f, 0.f);
                for (int q = 0; q < p; ++q) {
                    const float* np = n2p + (size_t)(q * 64 + b) * 128 + ob;
                    float4 n2 = make_float4(0.f, 0.f, 0.f, 0.f);
                    #pragma unroll
                    for (int qt = 0; qt < 4; ++qt)
                        n2 = f4add(n2, *(const float4*)(np + qt * 32));
                    float4 sv = *(const float4*)(s2 + ((size_t)q * 64 + b) * 512 + e4);
                    acc.x += squash_scale(n2.x) * sv.x;
                    acc.y += squash_scale(n2.y) * sv.y;
                    acc.z += squash_scale(n2.z) * sv.z;
                    acc.w += squash_scale(n2.w) * sv.w;
                }
                *(float4*)&vg[bq * 512 + e4] = acc;
            }
            __syncthreads();   // vg ready (and x_lds on first iteration)

            for (int bq = 0; bq < 4; ++bq) {
                const int b = g * 4 + bq;
                float4 xa = *(const float4*)&x_lds[b * 64 + w * 8];
                float4 xb = *(const float4*)&x_lds[b * 64 + w * 8 + 4];
                float xr[8] = {xa.x, xa.y, xa.z, xa.w, xb.x, xb.y, xb.z, xb.w};
                float uh[8];
                #pragma unroll
                for (int j = 0; j < 8; ++j) uh[j] = 0.f;
                #pragma unroll
                for (int d = 0; d < 8; ++d) {
                    #pragma unroll
                    for (int j = 0; j < 8; ++j)
                        uh[j] = fmaf(xr[d], Wr[d][j], uh[j]);
                }
                float c;
                if (p == 0) {
                    c = 0.03125f;               // softmax of zeros
                } else {
                    float logit = 0.f;
                    #pragma unroll
                    for (int j = 0; j < 8; ++j)
                        logit = fmaf(uh[j], vg[bq * 512 + (kk * 8 + j) * 32 + o], logit);
                    logit += __shfl_xor(logit, 32, 64);   // combine k-halves
                    float ex = __expf(logit);             // |logit| < ~2: no max needed
                    float sm = ex;
                    #pragma unroll
                    for (int off = 16; off >= 1; off >>= 1)
                        sm += __shfl_xor(sm, off, 64);    // softmax denom over o
                    c = __fdividef(ex, sm);
                }
                #pragma unroll
                for (int j = 0; j < 8; ++j)               // bank = o, 2-way(kk): free
                    red[(w * 4 + bq) * 512 + (kk * 8 + j) * 32 + o] = c * uh[j];
            }
            __syncthreads();   // red complete

            {   // fold 8 wave-slots -> per-chunk partial (b128 reads, coalesced store)
                const int bq = t >> 7;
                const int b  = g * 4 + bq;
                const int e4 = (t & 127) * 4;
                float4 s = make_float4(0.f, 0.f, 0.f, 0.f);
                #pragma unroll
                for (int slot = 0; slot < 8; ++slot)
                    s = f4add(s, *(const float4*)&red[(slot * 4 + bq) * 512 + e4]);
                *(float4*)(part + ((size_t)ch * 64 + b) * 512 + e4) = s;
            }
        }
        grid.sync();

        {   // reduceA: block (b = ch>>2, q = ch&3) sums its e-quarter over 256 chunks
            const int b   = ch >> 2, q = ch & 3;
            const int eq  = t & 31;
            const int cg0 = (t >> 5) * 16;
            const int e4  = q * 128 + eq * 4;
            float4 acc = make_float4(0.f, 0.f, 0.f, 0.f);
            for (int cc = cg0; cc < cg0 + 16; ++cc)
                acc = f4add(acc, *(const float4*)(part + ((size_t)cc * 64 + b) * 512 + e4));
            *(float4*)&red[t * 4] = acc;
            __syncthreads();
            if (t < 32) {
                float4 s = make_float4(0.f, 0.f, 0.f, 0.f);
                for (int gg = 0; gg < 16; ++gg)
                    s = f4add(s, *(const float4*)&red[(gg * 32 + t) * 4]);
                *(float4*)(s2 + ((size_t)p * 64 + b) * 512 + e4) = s;
                // per-o norm partial for this quarter:
                // lane t holds k = q*4+(t>>3), o = (t&7)*4 + component.
                float4 nn = make_float4(s.x * s.x, s.y * s.y, s.z * s.z, s.w * s.w);
                nn = f4add(nn, f4shfl_xor(nn, 8));    // sum over the
                nn = f4add(nn, f4shfl_xor(nn, 16));   // quarter's 4 k's
                if (t < 8)   // lane t -> o = t*4..t*4+3
                    *(float4*)(n2p + (size_t)(p * 64 + b) * 128 + q * 32 + t * 4) = nn;
            }
        }
        grid.sync();
    }

    {   // epilogue: v2 = squash(s2[2]) per (b,o) -> out[b][o][k]
        const int b = ch >> 2, q = ch & 3;
        if (t < 128) {
            const int e = q * 128 + t;
            const int oo = t & 31;
            const int k  = q * 4 + (t >> 5);
            const float* np = n2p + (size_t)(2 * 64 + b) * 128 + oo;
            float n2 = np[0] + np[32] + np[64] + np[96];
            float sv = s2[((size_t)2 * 64 + b) * 512 + e];
            out[(size_t)b * 512 + oo * 16 + k] = squash_scale(n2) * sv;
        }
    }
}

// ---------------------------------------------------------------------------
extern "C" void kernel_launch(void* const* d_in, const int* in_sizes, int n_in,
                              void* d_out, int out_size, void* d_ws, size_t ws_size,
                              hipStream_t stream)
{
    const float* x = (const float*)d_in[0];
    const float* W = (const float*)d_in[1];
    float* out = (float*)d_out;
    char* ws = (char*)d_ws;

    const size_t partB = (size_t)256 * 64 * 512 * 4;   // 32 MB
    const size_t s2B   = (size_t)3 * 64 * 512 * 4;     // 384 KB
    const size_t n2B   = (size_t)3 * 64 * 128 * 4;     // 96 KB
    if (ws_size < partB + s2B + n2B) return;           // never taken (ws ~33 MB)

    float* part = (float*)ws;
    float* s2   = (float*)(ws + partB);
    float* n2p  = (float*)(ws + partB + s2B);

    // idempotent, host-side: safe under graph capture
    hipFuncSetAttribute((const void*)caps_coop,
                        hipFuncAttributeMaxDynamicSharedMemorySize, LDSF * 4);

    void* args[] = { (void*)&x, (void*)&W, (void*)&part,
                     (void*)&s2, (void*)&n2p, (void*)&out };
    hipLaunchCooperativeKernel((void*)caps_coop, dim3(NB), dim3(NT),
                               args, (unsigned)(LDSF * 4), stream);
}

// Round 5
// 210.460 us; speedup vs baseline: 2.0280x; 2.0280x over previous
//
#include <hip/hip_runtime.h>

// B=64, I=2048, D=8, O=32, K=16.
// pass grid: 512 blocks = (h = bx>>8: b-half) x (ch = bx&255: 8-i chunk).
// Thread map: wave w = i-slot (8 i/chunk); lane l: o = l&31, kk = l>>5 (k-half).
// Per-thread W = W[i][o][:][kk*8..+8] = 64 floats, register-resident.
// part[ch][b][e], e = k*32+o. vsum kept in e-layout.

__device__ __forceinline__ float4 f4add(float4 a, float4 b) {
    return make_float4(a.x + b.x, a.y + b.y, a.z + b.z, a.w + b.w);
}

template<int PASS0>
__global__ __launch_bounds__(512, 4)   // 4 waves/EU -> 2 blocks/CU, VGPR<=128
void pass_kernel(const float* __restrict__ x,    // [64][2048][8]
                 const float* __restrict__ W,    // [2048][32][8][16]
                 const float* __restrict__ vin,  // [64][512] e-layout
                 float* __restrict__ part)       // [256][64][512]
{
    __shared__ __align__(16) float x_lds[32 * 64];   //  8 KB: [bl][il*8+d]
    __shared__ __align__(16) float red[8 * 2 * 512]; // 32 KB: [w*2+bq][e]
    __shared__ __align__(16) float vg[2 * 512];      //  4 KB: [bq][e]

    const int t  = threadIdx.x;
    const int w  = t >> 6;
    const int l  = t & 63;
    const int o  = l & 31;
    const int kk = l >> 5;
    const int bx = blockIdx.x;
    const int ch = bx & 255;
    const int h  = bx >> 8;          // b-half: b in [h*32, h*32+32)
    const int i  = ch * 8 + w;

    // ---- W[i][o][d][kk-half] -> 64 registers -------------------------------
    float Wr[8][8];
    {
        const float* wp = W + (size_t)(i * 32 + o) * 128 + kk * 8;
        #pragma unroll
        for (int d = 0; d < 8; ++d) {
            float4 a = *(const float4*)(wp + d * 16);
            float4 b = *(const float4*)(wp + d * 16 + 4);
            Wr[d][0] = a.x; Wr[d][1] = a.y; Wr[d][2] = a.z; Wr[d][3] = a.w;
            Wr[d][4] = b.x; Wr[d][5] = b.y; Wr[d][6] = b.z; Wr[d][7] = b.w;
        }
    }
    // ---- stage x[h-half, chunk, :]: 2048 floats, one float4/thread ---------
    {
        const int f  = t * 4;
        const int bl = f >> 6, r = f & 63;
        *(float4*)&x_lds[f] =
            *(const float4*)(x + (size_t)(h * 32 + bl) * 16384 + ch * 64 + r);
    }

    for (int g = 0; g < 16; ++g) {       // 2 b's per group
        if (!PASS0) {
            if (t < 256) {               // stage vsum for the group's 2 b's
                const int bq = t >> 7, idx = t & 127;
                const int b  = h * 32 + g * 2 + bq;
                *(float4*)&vg[bq * 512 + idx * 4] =
                    *(const float4*)(vin + (size_t)b * 512 + idx * 4);
            }
        }
        __syncthreads();                 // vg ready (and x_lds/red safe)

        #pragma unroll
        for (int bq = 0; bq < 2; ++bq) {
            const int bl = g * 2 + bq;
            float4 xa = *(const float4*)&x_lds[bl * 64 + w * 8];
            float4 xb = *(const float4*)&x_lds[bl * 64 + w * 8 + 4];
            float xr[8] = {xa.x, xa.y, xa.z, xa.w, xb.x, xb.y, xb.z, xb.w};
            float uh[8];
            #pragma unroll
            for (int j = 0; j < 8; ++j) uh[j] = 0.f;
            #pragma unroll
            for (int d = 0; d < 8; ++d) {
                #pragma unroll
                for (int j = 0; j < 8; ++j)
                    uh[j] = fmaf(xr[d], Wr[d][j], uh[j]);
            }
            float c;
            if (PASS0) {
                c = 0.03125f;            // softmax of zeros
            } else {
                float logit = 0.f;
                #pragma unroll
                for (int j = 0; j < 8; ++j)
                    logit = fmaf(uh[j], vg[bq * 512 + (kk * 8 + j) * 32 + o], logit);
                logit += __shfl_xor(logit, 32, 64);   // combine k-halves
                float ex = __expf(logit);             // |logit| small: no max
                float sm = ex;
                #pragma unroll
                for (int off = 16; off >= 1; off >>= 1)
                    sm += __shfl_xor(sm, off, 64);    // denom over 32 o's
                c = __fdividef(ex, sm);
            }
            #pragma unroll
            for (int j = 0; j < 8; ++j)               // bank=o, 2-way(kk): free
                red[(w * 2 + bq) * 512 + (kk * 8 + j) * 32 + o] = c * uh[j];
        }
        __syncthreads();                 // red complete

        if (t < 256) {                   // fold 8 i-slots -> per-chunk partial
            const int bq = t >> 7, e4 = (t & 127) * 4;
            float4 s = make_float4(0.f, 0.f, 0.f, 0.f);
            #pragma unroll
            for (int slot = 0; slot < 8; ++slot)
                s = f4add(s, *(const float4*)&red[(slot * 2 + bq) * 512 + e4]);
            const int b = h * 32 + g * 2 + bq;
            *(float4*)(part + ((size_t)ch * 64 + b) * 512 + e4) = s;
        }
        // no barrier needed: next group's first barrier orders red/vg reuse
    }
}

// ---------------------------------------------------------------------------
// Fused reduce: sum part over 256 chunks, per-(b,o) squash, vsum/out update.
// 64 blocks (one per b) x 1024 threads: e = t&511, cc-half = t>>9.
// PHASE 0: vsum = v; PHASE 1: vsum += v; PHASE 2: out[b][o][k] = v.
// ---------------------------------------------------------------------------
template<int PHASE>
__global__ __launch_bounds__(1024)
void reduce_kernel(const float* __restrict__ part,
                   float* __restrict__ vsum,
                   float* __restrict__ out)
{
    __shared__ float sred[512];
    __shared__ float wpart[8][32];
    const int b = blockIdx.x;
    const int t = threadIdx.x;
    const int e = t & 511;
    const int half = t >> 9;

    const float* p0 = part + (size_t)(half * 128) * 32768 + (size_t)b * 512 + e;
    float acc = 0.f;
    #pragma unroll 8
    for (int cc = 0; cc < 128; ++cc)
        acc += p0[(size_t)cc * 32768];

    if (half) sred[e] = acc;
    __syncthreads();

    float s = 0.f;
    if (!half) {
        s = acc + sred[e];
        float sq = s * s;
        sq += __shfl_xor(sq, 32, 64);              // pair the wave's 2 k's
        if ((t & 63) < 32) wpart[t >> 6][t & 31] = sq;
    }
    __syncthreads();

    if (!half) {
        float n2 = 0.f;
        #pragma unroll
        for (int ww = 0; ww < 8; ++ww) n2 += wpart[ww][t & 31];   // over 16 k
        float v = (n2 / (1.f + n2) * rsqrtf(n2 + 1e-7f)) * s;
        if (PHASE == 2)
            out[(size_t)b * 512 + (t & 31) * 16 + (t >> 5)] = v;  // [b][o][k]
        else if (PHASE == 1)
            vsum[(size_t)b * 512 + t] += v;
        else
            vsum[(size_t)b * 512 + t] = v;
    }
}

// ---------------------------------------------------------------------------
extern "C" void kernel_launch(void* const* d_in, const int* in_sizes, int n_in,
                              void* d_out, int out_size, void* d_ws, size_t ws_size,
                              hipStream_t stream)
{
    const float* x = (const float*)d_in[0];
    const float* W = (const float*)d_in[1];
    float* out = (float*)d_out;
    char* ws = (char*)d_ws;

    const size_t partB = (size_t)256 * 64 * 512 * 4;   // 32 MB
    const size_t vsumB = (size_t)64 * 512 * 4;         // 128 KB
    if (ws_size < partB + vsumB) return;               // ws ~33 MB: never taken

    float* part = (float*)ws;
    float* vsum = (float*)(ws + partB);

    // round 0: c uniform -> v0; vsum = v0
    pass_kernel<1><<<512, 512, 0, stream>>>(x, W, vsum, part);
    reduce_kernel<0><<<64, 1024, 0, stream>>>(part, vsum, out);
    // round 1: logits = u_hat . v0 -> v1; vsum = v0 + v1
    pass_kernel<0><<<512, 512, 0, stream>>>(x, W, vsum, part);
    reduce_kernel<1><<<64, 1024, 0, stream>>>(part, vsum, out);
    // round 2: logits = u_hat . (v0+v1) -> v2 = output
    pass_kernel<0><<<512, 512, 0, stream>>>(x, W, vsum, part);
    reduce_kernel<2><<<64, 1024, 0, stream>>>(part, vsum, out);
}

// Round 6
// 207.005 us; speedup vs baseline: 2.0619x; 1.0167x over previous
//
#include <hip/hip_runtime.h>

// B=64, I=2048, D=8, O=32, K=16.
// pass grid: 512 blocks = (h = bx>>8: b-half) x (ch = bx&255: 8-i chunk).
// Thread map: wave w = i-slot (8 i/chunk); lane l: o = l&31, kk = l>>5 (k-half).
// Per-thread W = W[i][o][:][kk*8..+8] = 64 floats, register-resident (asm-pinned).
// part[b][ch][e], e = k*32+o  (transposed so reduce streams contiguously).

__device__ __forceinline__ float4 f4add(float4 a, float4 b) {
    return make_float4(a.x + b.x, a.y + b.y, a.z + b.z, a.w + b.w);
}

template<int PASS0>
__global__ __launch_bounds__(512, 4)   // 4 waves/EU -> 2 blocks/CU, VGPR<=128
void pass_kernel(const float* __restrict__ x,    // [64][2048][8]
                 const float* __restrict__ W,    // [2048][32][8][16]
                 const float* __restrict__ vin,  // [64][512] e-layout
                 float* __restrict__ part)       // [64][256][512]
{
    __shared__ __align__(16) float x_lds[32 * 64];   //  8 KB: [bl][il*8+d]
    __shared__ __align__(16) float red[8 * 2 * 512]; // 32 KB: [w*2+bq][e]
    __shared__ __align__(16) float vg[2 * 512];      //  4 KB: [bq][e]

    const int t  = threadIdx.x;
    const int w  = t >> 6;
    const int l  = t & 63;
    const int o  = l & 31;
    const int kk = l >> 5;
    const int bx = blockIdx.x;
    const int ch = bx & 255;
    const int h  = bx >> 8;          // b-half: b in [h*32, h*32+32)
    const int i  = ch * 8 + w;

    // ---- W[i][o][d][kk-half] -> 64 registers, PINNED so the compiler cannot
    // sink/rematerialize the loads into the g-loop (R5: VGPR=60 proved it did).
    float Wr[8][8];
    {
        const float* wp = W + (size_t)(i * 32 + o) * 128 + kk * 8;
        #pragma unroll
        for (int d = 0; d < 8; ++d) {
            float4 a = *(const float4*)(wp + d * 16);
            float4 b = *(const float4*)(wp + d * 16 + 4);
            Wr[d][0] = a.x; Wr[d][1] = a.y; Wr[d][2] = a.z; Wr[d][3] = a.w;
            Wr[d][4] = b.x; Wr[d][5] = b.y; Wr[d][6] = b.z; Wr[d][7] = b.w;
        }
        #pragma unroll
        for (int d = 0; d < 8; ++d)
            #pragma unroll
            for (int j = 0; j < 8; ++j)
                asm volatile("" : "+v"(Wr[d][j]));   // force VGPR residency
    }
    // ---- stage x[h-half, chunk, :]: 2048 floats, one float4/thread ---------
    {
        const int f  = t * 4;
        const int bl = f >> 6, r = f & 63;
        *(float4*)&x_lds[f] =
            *(const float4*)(x + (size_t)(h * 32 + bl) * 16384 + ch * 64 + r);
    }

    for (int g = 0; g < 16; ++g) {       // 2 b's per group
        if (!PASS0) {
            if (t < 256) {               // stage vsum for the group's 2 b's
                const int bq = t >> 7, idx = t & 127;
                const int b  = h * 32 + g * 2 + bq;
                *(float4*)&vg[bq * 512 + idx * 4] =
                    *(const float4*)(vin + (size_t)b * 512 + idx * 4);
            }
        }
        __syncthreads();                 // vg ready (and x_lds/red safe)

        #pragma unroll
        for (int bq = 0; bq < 2; ++bq) {
            const int bl = g * 2 + bq;
            float4 xa = *(const float4*)&x_lds[bl * 64 + w * 8];
            float4 xb = *(const float4*)&x_lds[bl * 64 + w * 8 + 4];
            float xr[8] = {xa.x, xa.y, xa.z, xa.w, xb.x, xb.y, xb.z, xb.w};
            float uh[8];
            #pragma unroll
            for (int j = 0; j < 8; ++j) uh[j] = 0.f;
            #pragma unroll
            for (int d = 0; d < 8; ++d) {
                #pragma unroll
                for (int j = 0; j < 8; ++j)
                    uh[j] = fmaf(xr[d], Wr[d][j], uh[j]);
            }
            float c;
            if (PASS0) {
                c = 0.03125f;            // softmax of zeros
            } else {
                float logit = 0.f;
                #pragma unroll
                for (int j = 0; j < 8; ++j)
                    logit = fmaf(uh[j], vg[bq * 512 + (kk * 8 + j) * 32 + o], logit);
                logit += __shfl_xor(logit, 32, 64);   // combine k-halves
                float ex = __expf(logit);             // |logit| small: no max
                float sm = ex;
                #pragma unroll
                for (int off = 16; off >= 1; off >>= 1)
                    sm += __shfl_xor(sm, off, 64);    // denom over 32 o's
                c = __fdividef(ex, sm);
            }
            #pragma unroll
            for (int j = 0; j < 8; ++j)               // bank=o, 2-way(kk): free
                red[(w * 2 + bq) * 512 + (kk * 8 + j) * 32 + o] = c * uh[j];
        }
        __syncthreads();                 // red complete

        if (t < 256) {                   // fold 8 i-slots -> per-chunk partial
            const int bq = t >> 7, e4 = (t & 127) * 4;
            float4 s = make_float4(0.f, 0.f, 0.f, 0.f);
            #pragma unroll
            for (int slot = 0; slot < 8; ++slot)
                s = f4add(s, *(const float4*)&red[(slot * 2 + bq) * 512 + e4]);
            const int b = h * 32 + g * 2 + bq;
            *(float4*)(part + ((size_t)b * 256 + ch) * 512 + e4) = s;
        }
        // no barrier needed: next group's first barrier orders red/vg reuse
    }
}

// ---------------------------------------------------------------------------
// Fused reduce: sum part[b][*][e] over 256 chunks (contiguous 512 KB stream),
// per-(b,o) squash, vsum/out update. 64 blocks x 1024 threads: e=t&511,
// chunk-half = t>>9. PHASE 0: vsum=v; 1: vsum+=v; 2: out[b][o][k]=v.
// ---------------------------------------------------------------------------
template<int PHASE>
__global__ __launch_bounds__(1024)
void reduce_kernel(const float* __restrict__ part,
                   float* __restrict__ vsum,
                   float* __restrict__ out)
{
    __shared__ float sred[512];
    __shared__ float wpart[8][32];
    const int b = blockIdx.x;
    const int t = threadIdx.x;
    const int e = t & 511;
    const int half = t >> 9;

    const float* p0 = part + ((size_t)b * 256 + half * 128) * 512 + e;
    float acc = 0.f;
    #pragma unroll 8
    for (int cc = 0; cc < 128; ++cc)
        acc += p0[(size_t)cc * 512];

    if (half) sred[e] = acc;
    __syncthreads();

    float s = 0.f;
    if (!half) {
        s = acc + sred[e];
        float sq = s * s;
        sq += __shfl_xor(sq, 32, 64);              // pair the wave's 2 k's
        if ((t & 63) < 32) wpart[t >> 6][t & 31] = sq;
    }
    __syncthreads();

    if (!half) {
        float n2 = 0.f;
        #pragma unroll
        for (int ww = 0; ww < 8; ++ww) n2 += wpart[ww][t & 31];   // over 16 k
        float v = (n2 / (1.f + n2) * rsqrtf(n2 + 1e-7f)) * s;
        if (PHASE == 2)
            out[(size_t)b * 512 + (t & 31) * 16 + (t >> 5)] = v;  // [b][o][k]
        else if (PHASE == 1)
            vsum[(size_t)b * 512 + t] += v;
        else
            vsum[(size_t)b * 512 + t] = v;
    }
}

// ---------------------------------------------------------------------------
extern "C" void kernel_launch(void* const* d_in, const int* in_sizes, int n_in,
                              void* d_out, int out_size, void* d_ws, size_t ws_size,
                              hipStream_t stream)
{
    const float* x = (const float*)d_in[0];
    const float* W = (const float*)d_in[1];
    float* out = (float*)d_out;
    char* ws = (char*)d_ws;

    const size_t partB = (size_t)64 * 256 * 512 * 4;   // 32 MB
    const size_t vsumB = (size_t)64 * 512 * 4;         // 128 KB
    if (ws_size < partB + vsumB) return;               // ws ~33 MB: never taken

    float* part = (float*)ws;
    float* vsum = (float*)(ws + partB);

    // round 0: c uniform -> v0; vsum = v0
    pass_kernel<1><<<512, 512, 0, stream>>>(x, W, vsum, part);
    reduce_kernel<0><<<64, 1024, 0, stream>>>(part, vsum, out);
    // round 1: logits = u_hat . v0 -> v1; vsum = v0 + v1
    pass_kernel<0><<<512, 512, 0, stream>>>(x, W, vsum, part);
    reduce_kernel<1><<<64, 1024, 0, stream>>>(part, vsum, out);
    // round 2: logits = u_hat . (v0+v1) -> v2 = output
    pass_kernel<0><<<512, 512, 0, stream>>>(x, W, vsum, part);
    reduce_kernel<2><<<64, 1024, 0, stream>>>(part, vsum, out);
}